// Round 7
// baseline (719.395 us; speedup 1.0000x reference)
//
#include <hip/hip_runtime.h>

#define N_NODES 50000
#define N_EDGES 1600000
#define D 32

#define NPB 49                // nodes per bucket; bucket k = dst/49, max 1020
#define NBUCK 1024            // bucket table size (k <= 1020)
#define NAGG 1021             // aggregate blocks = buckets that contain nodes
#define SORT_BLOCKS 128
#define SORT_EPB 12500        // 128 * 12500 = 1.6M exactly
#define LB_STRIDE 1025

#define HIST_BLOCKS 128
#define HIST_EPB 12500
#define HWORDS 12500          // u8 x4 packed counts; 4*12500 = 50000 nodes exactly
#define NORM_HALF 49          // ceil(12500/256)

// ---------------------------------------------------------------------------
// K1: block-private degree histograms, u8x4 packed in LDS (50 KB).
// Grid 256: blocks 0..127 histogram src -> dumpA, 128..255 dst -> dumpB.
// Per-block per-node count <= ~10 (12500 edges over 50000 nodes) << 255.
// ---------------------------------------------------------------------------
__global__ __launch_bounds__(256) void hist_kernel(const int* __restrict__ src,
                                                   const int* __restrict__ dst,
                                                   unsigned int* __restrict__ dumpA,
                                                   unsigned int* __restrict__ dumpB) {
    __shared__ unsigned int h[HWORDS];
    int b = blockIdx.x;
    const int* idx = (b < HIST_BLOCKS) ? src : dst;
    unsigned int* dump = (b < HIST_BLOCKS) ? dumpA : dumpB;
    int chunk = (b < HIST_BLOCKS) ? b : b - HIST_BLOCKS;

    int t = threadIdx.x;
    for (int i = t; i < HWORDS; i += 256) h[i] = 0u;
    __syncthreads();
    int e0 = chunk * HIST_EPB;
    for (int i = t; i < HIST_EPB; i += 256) {
        int s = idx[e0 + i];
        atomicAdd(&h[s >> 2], 1u << (8 * (s & 3)));  // LDS, returnless
    }
    __syncthreads();
    unsigned int* o = dump + (size_t)chunk * HWORDS;
    for (int i = t; i < HWORDS; i += 256) o[i] = h[i];
}

// ---------------------------------------------------------------------------
// K2: reduce histograms -> norms. Grid 98:
//   blocks 0..48  : dumpA -> norm_out, fused xs1 = x * norm_out
//   blocks 49..97 : dumpB -> norm_in
// Each thread owns one packed word = 4 consecutive nodes.
// ---------------------------------------------------------------------------
__global__ __launch_bounds__(256) void norm_kernel(const unsigned int* __restrict__ dumpA,
                                                   const unsigned int* __restrict__ dumpB,
                                                   float* __restrict__ norm_out,
                                                   float* __restrict__ norm_in,
                                                   const float* __restrict__ x,
                                                   float* __restrict__ xs1) {
    int blk = blockIdx.x;
    bool outs = (blk < NORM_HALF);
    int w = (outs ? blk : blk - NORM_HALF) * 256 + threadIdx.x;
    if (w >= HWORDS) return;
    const unsigned int* dump = outs ? dumpA : dumpB;

    unsigned int a0 = 0, a1 = 0, a2 = 0, a3 = 0;
    for (int b = 0; b < HIST_BLOCKS; ++b) {
        unsigned int v = dump[(size_t)b * HWORDS + w];
        a0 += v & 0xFFu;
        a1 += (v >> 8) & 0xFFu;
        a2 += (v >> 16) & 0xFFu;
        a3 += (v >> 24);
    }
    float n[4];
    n[0] = a0 ? rsqrtf((float)a0) : 0.f;
    n[1] = a1 ? rsqrtf((float)a1) : 0.f;
    n[2] = a2 ? rsqrtf((float)a2) : 0.f;
    n[3] = a3 ? rsqrtf((float)a3) : 0.f;

    int node = 4 * w;  // 4*12500 = 50000 exactly, no guard needed
    float* norm = outs ? norm_out : norm_in;
    norm[node + 0] = n[0];
    norm[node + 1] = n[1];
    norm[node + 2] = n[2];
    norm[node + 3] = n[3];

    if (outs) {
        const float4* xin = (const float4*)(x + (size_t)node * D);
        float4* xout = (float4*)(xs1 + (size_t)node * D);
#pragma unroll
        for (int r = 0; r < 4; ++r) {
            float nn = n[r];
#pragma unroll
            for (int q = 0; q < 8; ++q) {
                float4 v = xin[r * 8 + q];
                v.x *= nn; v.y *= nn; v.z *= nn; v.w *= nn;
                xout[r * 8 + q] = v;
            }
        }
    }
}

// ---------------------------------------------------------------------------
// K3: per-block local counting sort by bucket (dst/49). No global atomics.
// Emits: pairbuf[block*12500 ...] = packed (src | local_dst<<16), sorted by
// bucket; lbase_g[block*1025 + k] = local exclusive prefix of bucket k.
// ---------------------------------------------------------------------------
__global__ __launch_bounds__(256) void bucket_sort_kernel(const int* __restrict__ src,
                                                          const int* __restrict__ dst,
                                                          unsigned int* __restrict__ pairbuf,
                                                          int* __restrict__ lbase_g) {
    __shared__ unsigned int sorted[SORT_EPB];  // 50 KB
    __shared__ int cnt[NBUCK];                 // counts, then cursors
    __shared__ int lbase[NBUCK + 1];
    __shared__ int part[256];

    int t = threadIdx.x;
    int e0 = blockIdx.x * SORT_EPB;

    for (int i = t; i < NBUCK; i += 256) cnt[i] = 0;
    __syncthreads();
    for (int i = t; i < SORT_EPB; i += 256) {
        int d = dst[e0 + i];
        atomicAdd(&cnt[d / NPB], 1);  // LDS, returnless
    }
    __syncthreads();

    // chunked exclusive scan over cnt[1024]: thread owns 4 consecutive
    int b4 = t * 4;
    int s0 = cnt[b4], s1 = cnt[b4 + 1], s2 = cnt[b4 + 2], s3 = cnt[b4 + 3];
    int mysum = s0 + s1 + s2 + s3;
    part[t] = mysum;
    __syncthreads();
    for (int off = 1; off < 256; off <<= 1) {
        int add = (t >= off) ? part[t - off] : 0;
        __syncthreads();
        part[t] += add;
        __syncthreads();
    }
    int run = part[t] - mysum;
    lbase[b4 + 0] = run;
    lbase[b4 + 1] = run + s0;
    lbase[b4 + 2] = run + s0 + s1;
    lbase[b4 + 3] = run + s0 + s1 + s2;
    if (t == 255) lbase[NBUCK] = part[255];  // == SORT_EPB
    __syncthreads();
    for (int i = t; i < NBUCK; i += 256) cnt[i] = lbase[i];  // cursors
    __syncthreads();

    for (int i = t; i < SORT_EPB; i += 256) {
        int d = dst[e0 + i];
        int s = src[e0 + i];
        int k = d / NPB;
        int pos = atomicAdd(&cnt[k], 1);  // LDS, with return
        sorted[pos] = (unsigned int)s | ((unsigned int)(d - k * NPB) << 16);
    }
    __syncthreads();

    unsigned int* po = pairbuf + (size_t)blockIdx.x * SORT_EPB;
    for (int i = t; i < SORT_EPB; i += 256) po[i] = sorted[i];
    int* lo = lbase_g + blockIdx.x * LB_STRIDE;
    for (int i = t; i <= NBUCK; i += 256) lo[i] = lbase[i];
}

// ---------------------------------------------------------------------------
// K4/K5: per-bucket aggregate + fused norm*GEMM+bias (+relu*norm_out).
// One block per 49-node bucket; LDS float accumulator (lane j -> bank j).
// Wave processes segments interleaved; 8 gathers in flight per chunk.
// ---------------------------------------------------------------------------
template <int IS_L1>
__global__ __launch_bounds__(256) void aggregate_kernel(const int* __restrict__ lbase_g,
                                                        const unsigned int* __restrict__ pairbuf,
                                                        const float* __restrict__ xs,
                                                        const float* __restrict__ norm_in,
                                                        const float* __restrict__ norm_out,
                                                        const float* __restrict__ W,
                                                        const float* __restrict__ bias,
                                                        float* __restrict__ out) {
    __shared__ float acc[NPB * D];        // 6272 B
    __shared__ float sW[D * D];
    __shared__ float sB[D];
    __shared__ int segstart[SORT_BLOCKS];
    __shared__ int seglen[SORT_BLOCKS];

    int t = threadIdx.x;
    int k = blockIdx.x;
    int lo = k * NPB;
    int nb = min(NPB, N_NODES - lo);

    for (int i = t; i < NPB * D; i += 256) acc[i] = 0.f;
    for (int i = t; i < D * D; i += 256) sW[i] = W[i];
    if (t < D) sB[t] = bias[t];
    if (t < SORT_BLOCKS) {
        int lb0 = lbase_g[t * LB_STRIDE + k];
        int lb1 = lbase_g[t * LB_STRIDE + k + 1];
        segstart[t] = t * SORT_EPB + lb0;
        seglen[t] = lb1 - lb0;
    }
    __syncthreads();

    int wave = t >> 6;
    int lane = t & 63;
    int j = lane & 31;
    int half = lane >> 5;

    for (int b = wave; b < SORT_BLOCKS; b += 4) {
        int sbase = segstart[b];
        int len = seglen[b];
        for (int c = 0; c < len; c += 16) {
            unsigned int pk = 0u;
            if (lane < 16 && c + lane < len) pk = pairbuf[sbase + c + lane];
#pragma unroll
            for (int q = 0; q < 8; ++q) {
                int eoff = c + 2 * q + half;
                unsigned int pe = __shfl(pk, 2 * q + half);
                if (eoff < len) {
                    int s = pe & 0xFFFF;
                    int dl = pe >> 16;
                    atomicAdd(&acc[dl * D + j], xs[(size_t)s * D + j]);
                }
            }
        }
    }
    __syncthreads();

    if (nb <= 0) return;
    int r0 = t >> 5;  // 0..7
    for (int r = r0; r < nb; r += 8) {
        int node = lo + r;
        float o = 0.f;
#pragma unroll
        for (int kk = 0; kk < D; ++kk) o += acc[r * D + kk] * sW[kk * D + j];
        o = o * norm_in[node] + sB[j];
        if (IS_L1) o = fmaxf(o, 0.f) * norm_out[node];
        out[(size_t)node * D + j] = o;
    }
}

// ---------------------------------------------------------------------------
extern "C" void kernel_launch(void* const* d_in, const int* in_sizes, int n_in,
                              void* d_out, int out_size, void* d_ws, size_t ws_size,
                              hipStream_t stream) {
    const float* x  = (const float*)d_in[0];
    const int* src  = (const int*)d_in[1];
    const int* dst  = (const int*)d_in[2];
    const float* W1 = (const float*)d_in[3];
    const float* b1 = (const float*)d_in[4];
    const float* W2 = (const float*)d_in[5];
    const float* b2 = (const float*)d_in[6];
    float* out = (float*)d_out;

    // ---- workspace layout (~33 MB) ----
    int* wsI = (int*)d_ws;
    int* lbase_g          = wsI;                             // 128*1025 = 131200
    float* norm_out       = (float*)(wsI + 131200);          // 50000
    float* norm_in        = (float*)(wsI + 181200);          // 50000 (pad to 231216)
    unsigned int* pairbuf = (unsigned int*)(wsI + 231216);   // 1.6M
    unsigned int* dumpA   = (unsigned int*)(wsI + 1831216);  // 1.6M
    unsigned int* dumpB   = (unsigned int*)(wsI + 3431216);  // 1.6M
    float* xs1            = (float*)(wsI + 5031216);         // 1.6M
    float* xs2            = (float*)(wsI + 6631216);         // 1.6M

    // K1: src+dst histograms (one launch, 256 blocks)
    hist_kernel<<<2 * HIST_BLOCKS, 256, 0, stream>>>(src, dst, dumpA, dumpB);
    // K2: norms (+ fused xs1 = x*norm_out)
    norm_kernel<<<2 * NORM_HALF, 256, 0, stream>>>(dumpA, dumpB, norm_out, norm_in, x, xs1);
    // K3: per-block local bucket sort
    bucket_sort_kernel<<<SORT_BLOCKS, 256, 0, stream>>>(src, dst, pairbuf, lbase_g);
    // K4: layer 1 -> xs2 = relu(h1)*norm_out (pre-scaled layer-2 messages)
    aggregate_kernel<1><<<NAGG, 256, 0, stream>>>(lbase_g, pairbuf, xs1,
                                                  norm_in, norm_out, W1, b1, xs2);
    // K5: layer 2 -> final output
    aggregate_kernel<0><<<NAGG, 256, 0, stream>>>(lbase_g, pairbuf, xs2,
                                                  norm_in, norm_out, W2, b2, out);
}